// Round 2
// baseline (367.608 us; speedup 1.0000x reference)
//
#include <hip/hip_runtime.h>
#include <hip/hip_bf16.h>
#include <hip/hip_cooperative_groups.h>

namespace cg = cooperative_groups;

#define V 49152
#define NNZ 9
#define EPSV 1e-5f
#define SLOPE 0.1f
#define NB 768          // V / 64 row-tiles = cooperative grid (3 blocks/CU on 256 CUs)
#define RST 68          // epilogue transpose row stride (floats)

typedef __attribute__((ext_vector_type(8))) short bf16x8;   // 8 bf16 (4 VGPRs)
typedef __attribute__((ext_vector_type(4))) float f32x4;    // MFMA C/D

__device__ __forceinline__ float lo2f(unsigned u) { return __uint_as_float(u << 16); }
__device__ __forceinline__ float hi2f(unsigned u) { return __uint_as_float(u & 0xffff0000u); }
__device__ __forceinline__ unsigned short f2us(float f) {
    __hip_bfloat16 h = __float2bfloat16(f);
    return *(unsigned short*)&h;
}
__device__ __forceinline__ unsigned pk2(float a, float b) {
    return ((unsigned)f2us(a)) | (((unsigned)f2us(b)) << 16);
}
__device__ __forceinline__ void fma8(float* t, float a, uint4 u) {
    t[0] += a * lo2f(u.x); t[1] += a * hi2f(u.x);
    t[2] += a * lo2f(u.y); t[3] += a * hi2f(u.y);
    t[4] += a * lo2f(u.z); t[5] += a * hi2f(u.z);
    t[6] += a * lo2f(u.w); t[7] += a * hi2f(u.w);
}
__device__ __forceinline__ void fold8(float* t, uint4 p) {
    t[0] = 2.f*t[0] - lo2f(p.x); t[1] = 2.f*t[1] - hi2f(p.x);
    t[2] = 2.f*t[2] - lo2f(p.y); t[3] = 2.f*t[3] - hi2f(p.y);
    t[4] = 2.f*t[4] - lo2f(p.z); t[5] = 2.f*t[5] - hi2f(p.z);
    t[6] = 2.f*t[6] - lo2f(p.w); t[7] = 2.f*t[7] - hi2f(p.w);
}
__device__ __forceinline__ uint4 pack8(const float* t) {
    uint4 r;
    r.x = pk2(t[0], t[1]); r.y = pk2(t[2], t[3]);
    r.z = pk2(t[4], t[5]); r.w = pk2(t[6], t[7]);
    return r;
}
__device__ __forceinline__ void gload_lds16(const void* g, void* l) {
    __builtin_amdgcn_global_load_lds((__attribute__((address_space(1))) void*)g,
                                     (__attribute__((address_space(3))) void*)l, 16, 0, 0);
}

// ---- prep: convert+transpose weights to bf16 [kk][o][f]; zero GN partial buffers ----
__global__ __launch_bounds__(256) void prep_k(
    const float* __restrict__ W1, const float* __restrict__ Wr, const float* __restrict__ W2,
    unsigned short* __restrict__ Wt1, unsigned short* __restrict__ Wtr, unsigned short* __restrict__ Wt2,
    float* __restrict__ part)
{
    int i = blockIdx.x * 256 + threadIdx.x;
    if (i < 32768) {                 // Wt2[kk][o][f] = W2[kk][f][o], F=64
        int kk = i >> 12, rem = i & 4095, o = rem >> 6, f = rem & 63;
        Wt2[i] = f2us(W2[kk * 4096 + f * 64 + o]);
    } else if (i < 49152) {          // Wt1, F=32
        int j = i - 32768;
        int kk = j >> 11, rem = j & 2047, o = rem >> 5, f = rem & 31;
        Wt1[j] = f2us(W1[kk * 2048 + f * 64 + o]);
    } else if (i < 65536) {          // Wtr, F=32
        int j = i - 49152;
        int kk = j >> 11, rem = j & 2047, o = rem >> 5, f = rem & 31;
        Wtr[j] = f2us(Wr[kk * 2048 + f * 64 + o]);
    } else if (i < 66560) {
        part[i - 65536] = 0.f;
    }
}

// ============================================================================
// FUSED PATH: two cooperative kernels, 768 blocks x 256 threads (3 blocks/CU).
// Each block owns rows [64*bid, 64*bid+64); grid.sync between Chebyshev steps.
// ============================================================================

// chain1: reorder + 7 SpMM steps + fused conv1/res GEMM. T rows = [v][b*32+f], 64 bf16.
__global__ __launch_bounds__(256, 3) void chain1_k(
    const float* __restrict__ x, const float* __restrict__ vals, const int* __restrict__ col,
    unsigned short* __restrict__ TS,
    const unsigned short* __restrict__ Wt1, const unsigned short* __restrict__ Wtr,
    const float* __restrict__ biasA, const float* __restrict__ biasB,
    unsigned short* __restrict__ ACC, float* __restrict__ resOut, float* __restrict__ part)
{
    cg::grid_group grid = cg::this_grid();
    __shared__ __align__(16) float epi[2 * 64 * RST];   // 34816 B; tiles overlay in front
    __shared__ float sGrp[32];
    uint4* tiles = (uint4*)epi;          // 2 x [64][8] uint4 (16 KB)

    const int tid = threadIdx.x;
    const int wv = tid >> 6, lane = tid & 63;
    const int quad = lane >> 4, l15 = lane & 15;
    const int ot = wv;                   // wave's o-subtile (baseline structure)
    const int v0 = blockIdx.x * 64;
    const int sr = tid >> 2, sc2 = (tid & 3) * 2;   // spmm: row, chunk base (2 uint4)
    const int sv = v0 + sr;

    f32x4 acc[4][2], accd[4][2];
    #pragma unroll
    for (int m = 0; m < 4; ++m)
        #pragma unroll
        for (int b = 0; b < 2; ++b) {
            acc[m][b]  = (f32x4){0.f, 0.f, 0.f, 0.f};
            accd[m][b] = (f32x4){0.f, 0.f, 0.f, 0.f};
        }

    auto do_mfma = [&](int kk, const unsigned short* tile_sh) {
        size_t brow = ((size_t)kk * 64 + ot * 16 + l15) * 32 + quad * 8;
        bf16x8 bw = *(const bf16x8*)(const void*)(Wt1 + brow);
        bf16x8 bd = *(const bf16x8*)(const void*)(Wtr + brow);
        #pragma unroll
        for (int m = 0; m < 4; ++m) {
            int r = m * 16 + l15, r7 = r & 7;
            const unsigned short* rb = tile_sh + (size_t)r * 64;
            #pragma unroll
            for (int b = 0; b < 2; ++b) {
                int s0 = (b * 4 + quad) ^ r7;       // CPR=8 XOR swizzle
                bf16x8 a = *(const bf16x8*)(const void*)(rb + s0 * 8);
                acc[m][b]  = __builtin_amdgcn_mfma_f32_16x16x32_bf16(a, bw, acc[m][b], 0, 0, 0);
                accd[m][b] = __builtin_amdgcn_mfma_f32_16x16x32_bf16(a, bd, accd[m][b], 0, 0, 0);
            }
        }
    };

    // phase 0: reorder x -> T0 (own rows), global + LDS buf0
    #pragma unroll
    for (int j = 0; j < 2; ++j) {
        int cid = tid + 256 * j;            // 0..511
        int r = cid >> 3, c = cid & 7;
        int b = c >> 2, f0 = (c & 3) * 8;
        const float* p = x + ((size_t)b * V + v0 + r) * 32 + f0;
        float4 a0 = *(const float4*)(const void*)p;
        float4 a1 = *(const float4*)(const void*)(p + 4);
        uint4 pk;
        pk.x = pk2(a0.x, a0.y); pk.y = pk2(a0.z, a0.w);
        pk.z = pk2(a1.x, a1.y); pk.w = pk2(a1.z, a1.w);
        *(uint4*)(void*)(TS + (size_t)(v0 + r) * 64 + c * 8) = pk;
        tiles[r * 8 + (c ^ (r & 7))] = pk;
    }
    __syncthreads();
    do_mfma(0, (const unsigned short*)tiles);
    __threadfence();
    grid.sync();
    __threadfence();

    // Chebyshev steps k = 1..7
    for (int k = 1; k < 8; ++k) {
        const unsigned short* zc = TS + (size_t)(k - 1) * V * 64;
        unsigned short* zn = TS + (size_t)k * V * 64;
        uint4* bufW = tiles + (k & 1) * 512;
        float t[16];
        #pragma unroll
        for (int i = 0; i < 16; ++i) t[i] = 0.f;
        int base = sv * NNZ;
        #pragma unroll
        for (int n = 0; n < NNZ; ++n) {
            float a = vals[base + n];
            int cc = col[base + n];
            const uint4* p = (const uint4*)(const void*)(zc + (size_t)cc * 64 + sc2 * 8);
            fma8(t, a, p[0]);
            fma8(t + 8, a, p[1]);
        }
        int s0 = sc2 ^ (sr & 7), s1 = (sc2 + 1) ^ (sr & 7);
        if (k >= 2) {                       // zp = T_{k-2}: self-owned chunk in buf[k&1]
            fold8(t,     bufW[sr * 8 + s0]);
            fold8(t + 8, bufW[sr * 8 + s1]);
        }
        uint4 r0 = pack8(t), r1 = pack8(t + 8);
        if (k < 7) {
            uint4* q = (uint4*)(void*)(zn + (size_t)sv * 64 + sc2 * 8);
            q[0] = r0; q[1] = r1;
        }
        bufW[sr * 8 + s0] = r0;
        bufW[sr * 8 + s1] = r1;
        __syncthreads();
        do_mfma(k, (const unsigned short*)bufW);
        if (k < 7) { __threadfence(); grid.sync(); __threadfence(); }
    }

    // epilogue: h1 -> ACC (bf16) + GN1 partials; res -> resOut (f32)
    __syncthreads();                        // tiles fully consumed before epi overlay
    int o = ot * 16 + l15;
    float biA = biasA[o], biB = biasB[o];
    #pragma unroll
    for (int m = 0; m < 4; ++m)
        #pragma unroll
        for (int b = 0; b < 2; ++b)
            #pragma unroll
            for (int rr = 0; rr < 4; ++rr) {
                int r = m * 16 + quad * 4 + rr;
                epi[(b * 64 + r) * RST + o] = acc[m][b][rr] + biA;
            }
    if (tid < 32) sGrp[tid] = 0.f;
    __syncthreads();
    #pragma unroll
    for (int j = 0; j < 4; ++j) {
        int cid = tid + 256 * j;            // 0..1023
        int g = cid & 7, r = (cid >> 3) & 63, b = cid >> 9;
        const float* src = epi + (b * 64 + r) * RST + g * 8;
        float e[8], s = 0.f, q = 0.f;
        #pragma unroll
        for (int i = 0; i < 8; ++i) { e[i] = src[i]; s += e[i]; q += e[i] * e[i]; }
        *(uint4*)(void*)(ACC + ((size_t)b * V + v0 + r) * 64 + g * 8) = pack8(e);
        atomicAdd(&sGrp[b * 8 + g], s);
        atomicAdd(&sGrp[16 + b * 8 + g], q);
    }
    __syncthreads();
    #pragma unroll
    for (int m = 0; m < 4; ++m)
        #pragma unroll
        for (int b = 0; b < 2; ++b)
            #pragma unroll
            for (int rr = 0; rr < 4; ++rr) {
                int r = m * 16 + quad * 4 + rr;
                epi[(b * 64 + r) * RST + o] = accd[m][b][rr] + biB;
            }
    __syncthreads();
    #pragma unroll
    for (int j = 0; j < 8; ++j) {
        int cid = tid + 256 * j;            // 0..2047 float4 chunks
        int oc = cid & 15, r = (cid >> 4) & 63, b = cid >> 10;
        float4 vv = *(const float4*)(const void*)(epi + (b * 64 + r) * RST + oc * 4);
        *(float4*)(void*)(resOut + ((size_t)b * V + v0 + r) * 64 + oc * 4) = vv;
    }
    if (tid < 16) {
        atomicAdd(&part[tid * 2],     sGrp[tid]);
        atomicAdd(&part[tid * 2 + 1], sGrp[16 + tid]);
    }
}

// chain2: GN1-apply + 7 SpMM steps + fused conv2 GEMM + GN2 + residual add.
// T rows = [v][b*64+o], 128 bf16 (256 B). Pre-GN h2 stays in registers/LDS.
__global__ __launch_bounds__(256, 3) void chain2_k(
    const unsigned short* __restrict__ ACC, const float* __restrict__ part1,
    const float* __restrict__ g1, const float* __restrict__ be1,
    unsigned short* __restrict__ TS, const unsigned short* __restrict__ Wt2,
    const float* __restrict__ biasA, float* __restrict__ part2,
    const float* __restrict__ g2, const float* __restrict__ be2,
    float* __restrict__ outres,
    const float* __restrict__ vals, const int* __restrict__ col)
{
    cg::grid_group grid = cg::this_grid();
    __shared__ __align__(16) float epi[2 * 64 * RST];   // 34816 B
    __shared__ float sGrp[32];
    uint4* tiles = (uint4*)epi;          // 2 x [64][16] uint4 (32 KB)

    const int tid = threadIdx.x;
    const int wv = tid >> 6, lane = tid & 63;
    const int quad = lane >> 4, l15 = lane & 15;
    const int ot = wv;
    const int v0 = blockIdx.x * 64;
    const int sr = tid >> 2, sc2 = (tid & 3) * 2;
    const int sv = v0 + sr;
    const float Nf = (float)V * 8.f;

    f32x4 acc[4][2];
    #pragma unroll
    for (int m = 0; m < 4; ++m)
        #pragma unroll
        for (int b = 0; b < 2; ++b) acc[m][b] = (f32x4){0.f, 0.f, 0.f, 0.f};

    auto do_mfma = [&](int kk, const unsigned short* tile_sh) {
        size_t brow = ((size_t)kk * 64 + ot * 16 + l15) * 64 + quad * 8;
        bf16x8 bw0 = *(const bf16x8*)(const void*)(Wt2 + brow);
        bf16x8 bw1 = *(const bf16x8*)(const void*)(Wt2 + brow + 32);
        #pragma unroll
        for (int m = 0; m < 4; ++m) {
            int r = m * 16 + l15, r7 = r & 7;
            const unsigned short* rb = tile_sh + (size_t)r * 128;
            #pragma unroll
            for (int b = 0; b < 2; ++b) {
                #pragma unroll
                for (int fh = 0; fh < 2; ++fh) {
                    int c0 = b * 8 + fh * 4 + quad;     // CPR=16
                    int s0 = (c0 & ~7) | ((c0 & 7) ^ r7);
                    bf16x8 a = *(const bf16x8*)(const void*)(rb + s0 * 8);
                    acc[m][b] = __builtin_amdgcn_mfma_f32_16x16x32_bf16(
                        a, fh ? bw1 : bw0, acc[m][b], 0, 0, 0);
                }
            }
        }
    };

    // phase 0: GN1 + LeakyReLU on own rows -> T0 global + LDS buf0
    {
        int cl = tid & 15;
        int b = cl >> 3, g = cl & 7, j8 = b * 8 + g;
        float mean = part1[j8 * 2] / Nf;
        float rstd = rsqrtf(part1[j8 * 2 + 1] / Nf - mean * mean + EPSV);
        int o0 = g * 8;
        float gm[8], bt[8];
        #pragma unroll
        for (int i = 0; i < 8; ++i) { gm[i] = g1[o0 + i]; bt[i] = be1[o0 + i]; }
        #pragma unroll
        for (int j = 0; j < 4; ++j) {
            int r = (tid >> 4) + 16 * j;
            int v = v0 + r;
            uint4 aa = *(const uint4*)(const void*)(ACC + ((size_t)b * V + v) * 64 + o0);
            float e[8] = { lo2f(aa.x), hi2f(aa.x), lo2f(aa.y), hi2f(aa.y),
                           lo2f(aa.z), hi2f(aa.z), lo2f(aa.w), hi2f(aa.w) };
            float y[8];
            #pragma unroll
            for (int i = 0; i < 8; ++i) {
                float t = (e[i] - mean) * rstd * gm[i] + bt[i];
                y[i] = t > 0.f ? t : SLOPE * t;
            }
            uint4 pk = pack8(y);
            *(uint4*)(void*)(TS + (size_t)v * 128 + cl * 8) = pk;
            tiles[r * 16 + ((cl & ~7) | ((cl & 7) ^ (r & 7)))] = pk;
        }
    }
    __syncthreads();
    do_mfma(0, (const unsigned short*)tiles);
    __threadfence();
    grid.sync();
    __threadfence();

    // Chebyshev steps k = 1..7
    for (int k = 1; k < 8; ++k) {
        const unsigned short* zc = TS + (size_t)(k - 1) * V * 128;
        unsigned short* zn = TS + (size_t)k * V * 128;
        uint4* bufW = tiles + (k & 1) * 1024;
        int base = sv * NNZ;
        float av[NNZ]; int ac[NNZ];
        #pragma unroll
        for (int n = 0; n < NNZ; ++n) { av[n] = vals[base + n]; ac[n] = col[base + n]; }
        #pragma unroll
        for (int h = 0; h < 2; ++h) {       // two 128B half-rows
            int c = h * 8 + sc2;
            float t[16];
            #pragma unroll
            for (int i = 0; i < 16; ++i) t[i] = 0.f;
            #pragma unroll
            for (int n = 0; n < NNZ; ++n) {
                const uint4* p = (const uint4*)(const void*)(zc + (size_t)ac[n] * 128 + c * 8);
                fma8(t, av[n], p[0]);
                fma8(t + 8, av[n], p[1]);
            }
            int s0 = (c & ~7) | ((c & 7) ^ (sr & 7));
            int s1 = (c & ~7) | (((c + 1) & 7) ^ (sr & 7));
            if (k >= 2) {
                fold8(t,     bufW[sr * 16 + s0]);
                fold8(t + 8, bufW[sr * 16 + s1]);
            }
            uint4 r0 = pack8(t), r1 = pack8(t + 8);
            if (k < 7) {
                uint4* q = (uint4*)(void*)(zn + (size_t)sv * 128 + c * 8);
                q[0] = r0; q[1] = r1;
            }
            bufW[sr * 16 + s0] = r0;
            bufW[sr * 16 + s1] = r1;
        }
        __syncthreads();
        do_mfma(k, (const unsigned short*)bufW);
        if (k < 7) { __threadfence(); grid.sync(); __threadfence(); }
    }

    // epilogue A: stage pre-GN h2 in LDS, accumulate GN2 partials, publish stats
    __syncthreads();
    int o = ot * 16 + l15;
    float biA = biasA[o];
    #pragma unroll
    for (int m = 0; m < 4; ++m)
        #pragma unroll
        for (int b = 0; b < 2; ++b)
            #pragma unroll
            for (int rr = 0; rr < 4; ++rr) {
                int r = m * 16 + quad * 4 + rr;
                epi[(b * 64 + r) * RST + o] = acc[m][b][rr] + biA;
            }
    if (tid < 32) sGrp[tid] = 0.f;
    __syncthreads();
    #pragma unroll
    for (int j = 0; j < 4; ++j) {
        int cid = tid + 256 * j;
        int g = cid & 7, r = (cid >> 3) & 63, b = cid >> 9;
        const float* src = epi + (b * 64 + r) * RST + g * 8;
        float s = 0.f, q = 0.f;
        #pragma unroll
        for (int i = 0; i < 8; ++i) { float e = src[i]; s += e; q += e * e; }
        atomicAdd(&sGrp[b * 8 + g], s);
        atomicAdd(&sGrp[16 + b * 8 + g], q);
    }
    __syncthreads();
    if (tid < 16) {
        atomicAdd(&part2[tid * 2],     sGrp[tid]);
        atomicAdd(&part2[tid * 2 + 1], sGrp[16 + tid]);
    }
    __threadfence();
    grid.sync();
    __threadfence();

    // epilogue B: GN2 + LeakyReLU from LDS (f32) + residual add
    {
        int cl = tid & 15;
        int b = cl >> 3, g = cl & 7, j8 = b * 8 + g;
        float mean = part2[j8 * 2] / Nf;
        float rstd = rsqrtf(part2[j8 * 2 + 1] / Nf - mean * mean + EPSV);
        int o0 = g * 8;
        float gm[8], bt[8];
        #pragma unroll
        for (int i = 0; i < 8; ++i) { gm[i] = g2[o0 + i]; bt[i] = be2[o0 + i]; }
        #pragma unroll
        for (int j = 0; j < 4; ++j) {
            int r = (tid >> 4) + 16 * j;
            const float* src = epi + (b * 64 + r) * RST + o0;
            float y[8];
            #pragma unroll
            for (int i = 0; i < 8; ++i) {
                float t = (src[i] - mean) * rstd * gm[i] + bt[i];
                y[i] = t > 0.f ? t : SLOPE * t;
            }
            size_t gb = ((size_t)b * V + v0 + r) * 64 + o0;
            float4 r0 = *(const float4*)(const void*)(outres + gb);
            float4 r1 = *(const float4*)(const void*)(outres + gb + 4);
            float4 w0 = { y[0] + r0.x, y[1] + r0.y, y[2] + r0.z, y[3] + r0.w };
            float4 w1 = { y[4] + r1.x, y[5] + r1.y, y[6] + r1.z, y[7] + r1.w };
            *(float4*)(void*)(outres + gb) = w0;
            *(float4*)(void*)(outres + gb + 4) = w1;
        }
    }
}

// ============================================================================
// FALLBACK PATH: proven round-0 multi-kernel pipeline (364 µs)
// ============================================================================
__global__ __launch_bounds__(256) void reorder_k(const float* __restrict__ x, unsigned* __restrict__ t0) {
    int idx = blockIdx.x * 256 + threadIdx.x;
    int v = idx >> 5, j2 = idx & 31;
    int b = j2 >> 4, f0 = (j2 & 15) * 2;
    const float* p = x + ((size_t)b * V + v) * 32 + f0;
    t0[idx] = pk2(p[0], p[1]);
}

template<int THR, bool FIRST>
__global__ __launch_bounds__(256) void spmm_step(
    const uint4* __restrict__ zc, const uint4* __restrict__ zp, uint4* __restrict__ zn,
    const float* __restrict__ vals, const int* __restrict__ col)
{
    constexpr int L4 = THR * 2;
    int tid = blockIdx.x * 256 + threadIdx.x;
    int v = tid / THR;
    int c = (tid - v * THR) * 2;
    int base = v * NNZ;
    float t[16];
    #pragma unroll
    for (int i = 0; i < 16; ++i) t[i] = 0.f;
    #pragma unroll
    for (int n = 0; n < NNZ; ++n) {
        float a = vals[base + n];
        int cc = col[base + n];
        const uint4* p = zc + (size_t)cc * L4 + c;
        fma8(t, a, p[0]);
        fma8(t + 8, a, p[1]);
    }
    if (!FIRST) {
        const uint4* pp = zp + (size_t)v * L4 + c;
        fold8(t, pp[0]);
        fold8(t + 8, pp[1]);
    }
    uint4* q = zn + (size_t)v * L4 + c;
    q[0] = pack8(t);
    q[1] = pack8(t + 8);
}

template<int F, int NKK, int NPH, bool DUAL, bool INIT, bool FINAL>
__global__ __launch_bounds__(256) void mfma_gemm(
    const unsigned short* __restrict__ T,
    const unsigned short* __restrict__ WtA, const unsigned short* __restrict__ WtB,
    const float* __restrict__ biasA, const float* __restrict__ biasB,
    unsigned short* __restrict__ ACC, float* __restrict__ resOut,
    float* __restrict__ part)
{
    constexpr int KPP = NKK / NPH;
    constexpr int CPR = F / 4;
    constexpr int FH = F / 32;
    constexpr int STAGE_SH = KPP * 64 * 2 * F;
    constexpr int TRANS_SH = (DUAL ? 2 : 1) * 2 * 64 * RST * 2;
    constexpr int SH = STAGE_SH > TRANS_SH ? STAGE_SH : TRANS_SH;
    __shared__ unsigned short shraw[SH];
    __shared__ float sGrp[32];

    unsigned short* tile = shraw;
    float* accbuf  = (float*)shraw;
    float* dualbuf = accbuf + 2 * 64 * RST;

    int wv = threadIdx.x >> 6, lane = threadIdx.x & 63;
    int quad = lane >> 4, l15 = lane & 15;
    int v0 = blockIdx.x * 64;
    int ot = wv;

    bf16x8 bw[NKK][FH];
    bf16x8 bd[NKK][FH];
    f32x4 acc[4][2];
    f32x4 accd[4][2];

    #pragma unroll
    for (int ph = 0; ph < NPH; ++ph) {
        if (ph > 0) __syncthreads();
        #pragma unroll
        for (int i = 0; i < (KPP * 64 * CPR) / 256; ++i) {
            int s = (i * 4 + wv) * 64 + lane;
            int kkl = s / (64 * CPR);
            int ws = s - kkl * 64 * CPR;
            int row = ws / CPR;
            int cl = ws - row * CPR;
            int cg = (cl & ~7) | ((cl & 7) ^ (row & 7));
            const unsigned short* gp =
                T + ((size_t)(ph * KPP + kkl) * V + v0 + row) * (2 * F) + cg * 8;
            gload_lds16(gp, tile + (size_t)(i * 4 + wv) * 64 * 8);
        }
        if (ph == 0) {
            #pragma unroll
            for (int kk = 0; kk < NKK; ++kk)
                #pragma unroll
                for (int fh = 0; fh < FH; ++fh) {
                    size_t brow = ((size_t)kk * 64 + ot * 16 + l15) * F + fh * 32 + quad * 8;
                    bw[kk][fh] = *(const bf16x8*)(const void*)(WtA + brow);
                    if constexpr (DUAL) bd[kk][fh] = *(const bf16x8*)(const void*)(WtB + brow);
                }
            #pragma unroll
            for (int m = 0; m < 4; ++m)
                #pragma unroll
                for (int b = 0; b < 2; ++b) {
                    acc[m][b] = (f32x4){0.f, 0.f, 0.f, 0.f};
                    if constexpr (DUAL) accd[m][b] = (f32x4){0.f, 0.f, 0.f, 0.f};
                }
        }
        __syncthreads();
        #pragma unroll
        for (int kkl = 0; kkl < KPP; ++kkl) {
            int kk = ph * KPP + kkl;
            #pragma unroll
            for (int fh = 0; fh < FH; ++fh)
                #pragma unroll
                for (int m = 0; m < 4; ++m) {
                    int r = m * 16 + l15;
                    int rx = r & 7;
                    const unsigned short* rbase = tile + ((size_t)kkl * 64 + r) * 2 * F;
                    #pragma unroll
                    for (int b = 0; b < 2; ++b) {
                        int c0 = b * (CPR / 2) + fh * 4 + quad;
                        int s0 = (c0 & ~7) | ((c0 & 7) ^ rx);
                        bf16x8 a = *(const bf16x8*)(const void*)(rbase + s0 * 8);
                        acc[m][b] = __builtin_amdgcn_mfma_f32_16x16x32_bf16(a, bw[kk][fh], acc[m][b], 0, 0, 0);
                        if constexpr (DUAL)
                            accd[m][b] = __builtin_amdgcn_mfma_f32_16x16x32_bf16(a, bd[kk][fh], accd[m][b], 0, 0, 0);
                    }
                }
        }
    }

    __syncthreads();
    int o = ot * 16 + l15;
    float bia = FINAL ? biasA[o] : 0.f;
    float biaB = DUAL ? biasB[o] : 0.f;
    #pragma unroll
    for (int m = 0; m < 4; ++m)
        #pragma unroll
        for (int b = 0; b < 2; ++b)
            #pragma unroll
            for (int rr = 0; rr < 4; ++rr) {
                int r = m * 16 + quad * 4 + rr;
                accbuf[(b * 64 + r) * RST + o] = acc[m][b][rr] + bia;
                if constexpr (DUAL) dualbuf[(b * 64 + r) * RST + o] = accd[m][b][rr] + biaB;
            }
    if constexpr (FINAL) {
        if (threadIdx.x < 32) sGrp[threadIdx.x] = 0.f;
    }
    __syncthreads();
    #pragma unroll
    for (int j = 0; j < 4; ++j) {
        int cid = threadIdx.x + 256 * j;
        int g = cid & 7, r = (cid >> 3) & 63, b = cid >> 9;
        int o0 = g * 8;
        const float* src = accbuf + (b * 64 + r) * RST + o0;
        float e[8];
        #pragma unroll
        for (int i = 0; i < 8; ++i) e[i] = src[i];
        size_t gidx = ((size_t)b * V + v0 + r) * 64 + o0;
        if constexpr (!INIT) {
            uint4 old = *(const uint4*)(const void*)(ACC + gidx);
            e[0] += lo2f(old.x); e[1] += hi2f(old.x);
            e[2] += lo2f(old.y); e[3] += hi2f(old.y);
            e[4] += lo2f(old.z); e[5] += hi2f(old.z);
            e[6] += lo2f(old.w); e[7] += hi2f(old.w);
        }
        *(uint4*)(void*)(ACC + gidx) = pack8(e);
        if constexpr (FINAL) {
            float s = 0.f, q = 0.f;
            #pragma unroll
            for (int i = 0; i < 8; ++i) { s += e[i]; q += e[i] * e[i]; }
            atomicAdd(&sGrp[b * 8 + g], s);
            atomicAdd(&sGrp[16 + b * 8 + g], q);
        }
    }
    if constexpr (DUAL) {
        #pragma unroll
        for (int j = 0; j < 8; ++j) {
            int cid = threadIdx.x + 256 * j;
            int oc = cid & 15, r = (cid >> 4) & 63, b = cid >> 10;
            float4 vv = *(const float4*)(const void*)(dualbuf + (b * 64 + r) * RST + oc * 4);
            *(float4*)(void*)(resOut + ((size_t)b * V + v0 + r) * 64 + oc * 4) = vv;
        }
    }
    if constexpr (FINAL) {
        __syncthreads();
        if (threadIdx.x < 16) {
            atomicAdd(&part[threadIdx.x * 2],     sGrp[threadIdx.x]);
            atomicAdd(&part[threadIdx.x * 2 + 1], sGrp[16 + threadIdx.x]);
        }
    }
}

__global__ __launch_bounds__(256) void gn_apply(const unsigned short* __restrict__ ACC,
                                                const float* __restrict__ part,
                                                const float* __restrict__ gamma, const float* __restrict__ beta,
                                                unsigned* __restrict__ zout) {
    int idx = blockIdx.x * 256 + threadIdx.x;
    int v = idx >> 4, j = idx & 15;
    int b = j >> 3, g = j & 7;
    const float N = (float)V * 8.f;
    float mean = part[j * 2] / N;
    float rstd = rsqrtf(part[j * 2 + 1] / N - mean * mean + EPSV);
    int o0 = g * 8;
    uint4 aa = *(const uint4*)(const void*)(ACC + ((size_t)b * V + v) * 64 + o0);
    float e[8] = { lo2f(aa.x), hi2f(aa.x), lo2f(aa.y), hi2f(aa.y),
                   lo2f(aa.z), hi2f(aa.z), lo2f(aa.w), hi2f(aa.w) };
    float y[8];
    #pragma unroll
    for (int i = 0; i < 8; ++i) {
        float t = (e[i] - mean) * rstd * gamma[o0 + i] + beta[o0 + i];
        y[i] = t > 0.f ? t : SLOPE * t;
    }
    uint4 pk;
    pk.x = pk2(y[0], y[1]); pk.y = pk2(y[2], y[3]);
    pk.z = pk2(y[4], y[5]); pk.w = pk2(y[6], y[7]);
    *(uint4*)(void*)(zout + (size_t)v * 64 + b * 32 + g * 4) = pk;
}

__global__ __launch_bounds__(256) void final_out(const unsigned short* __restrict__ ACC,
                                                 float* outres,
                                                 const float* __restrict__ part,
                                                 const float* __restrict__ gamma, const float* __restrict__ beta) {
    int idx = blockIdx.x * 256 + threadIdx.x;
    int b = idx >= V * 8 ? 1 : 0;
    int r = idx - b * V * 8;
    int v = r >> 3, g = r & 7;
    int j = b * 8 + g;
    const float N = (float)V * 8.f;
    float mean = part[j * 2] / N;
    float rstd = rsqrtf(part[j * 2 + 1] / N - mean * mean + EPSV);
    int o0 = g * 8;
    size_t base = ((size_t)b * V + v) * 64 + o0;
    uint4 aa = *(const uint4*)(const void*)(ACC + base);
    float e[8] = { lo2f(aa.x), hi2f(aa.x), lo2f(aa.y), hi2f(aa.y),
                   lo2f(aa.z), hi2f(aa.z), lo2f(aa.w), hi2f(aa.w) };
    float4 r0 = *(const float4*)(const void*)(outres + base);
    float4 r1 = *(const float4*)(const void*)(outres + base + 4);
    float y[8];
    #pragma unroll
    for (int i = 0; i < 8; ++i) {
        float t = (e[i] - mean) * rstd * gamma[o0 + i] + beta[o0 + i];
        y[i] = t > 0.f ? t : SLOPE * t;
    }
    float4 w0 = { y[0] + r0.x, y[1] + r0.y, y[2] + r0.z, y[3] + r0.w };
    float4 w1 = { y[4] + r1.x, y[5] + r1.y, y[6] + r1.z, y[7] + r1.w };
    *(float4*)(void*)(outres + base) = w0;
    *(float4*)(void*)(outres + base + 4) = w1;
}

extern "C" void kernel_launch(void* const* d_in, const int* in_sizes, int n_in,
                              void* d_out, int out_size, void* d_ws, size_t ws_size,
                              hipStream_t stream) {
    const float* x    = (const float*)d_in[0];
    const float* vals = (const float*)d_in[1];
    const int*   col  = (const int*)d_in[3];
    const float* W1   = (const float*)d_in[4];
    const float* b1   = (const float*)d_in[5];
    const float* g1   = (const float*)d_in[6];
    const float* be1  = (const float*)d_in[7];
    const float* W2   = (const float*)d_in[8];
    const float* b2   = (const float*)d_in[9];
    const float* g2   = (const float*)d_in[10];
    const float* be2  = (const float*)d_in[11];
    const float* Wr   = (const float*)d_in[12];
    const float* br   = (const float*)d_in[13];
    float* out = (float*)d_out;

    unsigned short* TS  = (unsigned short*)d_ws;
    unsigned short* ACC = TS + (size_t)8 * V * 128;
    unsigned short* Wt1 = ACC + (size_t)2 * V * 64;
    unsigned short* Wtr = Wt1 + 8 * 64 * 32;
    unsigned short* Wt2 = Wtr + 8 * 64 * 32;
    float* PART1 = (float*)(Wt2 + 8 * 64 * 64);
    float* PART2 = PART1 + 32;

    prep_k<<<260, 256, 0, stream>>>(W1, Wr, W2, Wt1, Wtr, Wt2, PART1);

    // occupancy gate: fused path needs 3 co-resident blocks/CU for both chains
    static int coop_ok = -1;
    if (coop_ok < 0) {
        int o1 = 0, o2 = 0;
        hipError_t e1 = hipOccupancyMaxActiveBlocksPerMultiprocessor(
            &o1, (const void*)chain1_k, 256, 0);
        hipError_t e2 = hipOccupancyMaxActiveBlocksPerMultiprocessor(
            &o2, (const void*)chain2_k, 256, 0);
        coop_ok = (e1 == hipSuccess && e2 == hipSuccess && o1 >= 3 && o2 >= 3) ? 1 : 0;
    }

    int did_chain1 = 0, did_chain2 = 0;
    if (coop_ok == 1) {
        void* a1[] = { (void*)&x, (void*)&vals, (void*)&col, (void*)&TS, (void*)&Wt1, (void*)&Wtr,
                       (void*)&b1, (void*)&br, (void*)&ACC, (void*)&out, (void*)&PART1 };
        if (hipLaunchCooperativeKernel((const void*)chain1_k, dim3(NB), dim3(256), a1, 0, stream)
            == hipSuccess) {
            did_chain1 = 1;
            void* a2[] = { (void*)&ACC, (void*)&PART1, (void*)&g1, (void*)&be1, (void*)&TS, (void*)&Wt2,
                           (void*)&b2, (void*)&PART2, (void*)&g2, (void*)&be2, (void*)&out,
                           (void*)&vals, (void*)&col };
            if (hipLaunchCooperativeKernel((const void*)chain2_k, dim3(NB), dim3(256), a2, 0, stream)
                == hipSuccess) {
                did_chain2 = 1;
            }
        }
        if (!did_chain1 || !did_chain2) coop_ok = 0;   // don't retry fused path
    }

    if (!did_chain1) {
        // full fallback: conv1 basis + conv1/res GEMM
        uint4* T1s[8];
        for (int k = 0; k < 8; ++k) T1s[k] = (uint4*)(TS + (size_t)k * V * 64);
        reorder_k<<<V * 32 / 256, 256, 0, stream>>>(x, (unsigned*)T1s[0]);
        spmm_step<4, true><<<V * 4 / 256, 256, 0, stream>>>(T1s[0], nullptr, T1s[1], vals, col);
        for (int k = 2; k < 8; ++k)
            spmm_step<4, false><<<V * 4 / 256, 256, 0, stream>>>(T1s[k-1], T1s[k-2], T1s[k], vals, col);
        mfma_gemm<32, 8, 1, true, true, true><<<V / 64, 256, 0, stream>>>(
            TS, Wt1, Wtr, b1, br, ACC, out, PART1);
    }
    if (!did_chain2) {
        // conv2 fallback (works whether chain1 or fallback produced ACC/PART1/out)
        uint4* T2s[8];
        for (int k = 0; k < 8; ++k) T2s[k] = (uint4*)(TS + (size_t)k * V * 128);
        gn_apply<<<V * 16 / 256, 256, 0, stream>>>(ACC, PART1, g1, be1, (unsigned*)T2s[0]);
        spmm_step<8, true><<<V * 8 / 256, 256, 0, stream>>>(T2s[0], nullptr, T2s[1], vals, col);
        for (int k = 2; k < 8; ++k)
            spmm_step<8, false><<<V * 8 / 256, 256, 0, stream>>>(T2s[k-1], T2s[k-2], T2s[k], vals, col);
        mfma_gemm<64, 8, 2, false, true, true><<<V / 64, 256, 0, stream>>>(
            TS, Wt2, nullptr, b2, nullptr, ACC, nullptr, PART2);
        final_out<<<2 * V * 8 / 256, 256, 0, stream>>>(ACC, out, PART2, g2, be2);
    }
}

// Round 3
// 364.063 us; speedup vs baseline: 1.0097x; 1.0097x over previous
//
#include <hip/hip_runtime.h>
#include <hip/hip_bf16.h>

#define V 49152
#define NNZ 9
#define EPSV 1e-5f
#define SLOPE 0.1f
#define RST 68          // epilogue transpose row stride (floats)

typedef __attribute__((ext_vector_type(8))) short bf16x8;   // 8 bf16 (4 VGPRs)
typedef __attribute__((ext_vector_type(4))) float f32x4;    // MFMA C/D

__device__ __forceinline__ float lo2f(unsigned u) { return __uint_as_float(u << 16); }
__device__ __forceinline__ float hi2f(unsigned u) { return __uint_as_float(u & 0xffff0000u); }
__device__ __forceinline__ unsigned short f2us(float f) {
    __hip_bfloat16 h = __float2bfloat16(f);
    return *(unsigned short*)&h;
}
__device__ __forceinline__ unsigned pk2(float a, float b) {
    return ((unsigned)f2us(a)) | (((unsigned)f2us(b)) << 16);
}
__device__ __forceinline__ void fma8(float* t, float a, uint4 u) {
    t[0] += a * lo2f(u.x); t[1] += a * hi2f(u.x);
    t[2] += a * lo2f(u.y); t[3] += a * hi2f(u.y);
    t[4] += a * lo2f(u.z); t[5] += a * hi2f(u.z);
    t[6] += a * lo2f(u.w); t[7] += a * hi2f(u.w);
}
__device__ __forceinline__ void fold8(float* t, uint4 p) {
    t[0] = 2.f*t[0] - lo2f(p.x); t[1] = 2.f*t[1] - hi2f(p.x);
    t[2] = 2.f*t[2] - lo2f(p.y); t[3] = 2.f*t[3] - hi2f(p.y);
    t[4] = 2.f*t[4] - lo2f(p.z); t[5] = 2.f*t[5] - hi2f(p.z);
    t[6] = 2.f*t[6] - lo2f(p.w); t[7] = 2.f*t[7] - hi2f(p.w);
}
__device__ __forceinline__ uint4 pack8(const float* t) {
    uint4 r;
    r.x = pk2(t[0], t[1]); r.y = pk2(t[2], t[3]);
    r.z = pk2(t[4], t[5]); r.w = pk2(t[6], t[7]);
    return r;
}
// GN + LeakyReLU applied to one 8-channel bf16 chunk
__device__ __forceinline__ void gnleaky8(uint4 u, const float* scl, const float* sft, float* y) {
    float e[8] = { lo2f(u.x), hi2f(u.x), lo2f(u.y), hi2f(u.y),
                   lo2f(u.z), hi2f(u.z), lo2f(u.w), hi2f(u.w) };
    #pragma unroll
    for (int i = 0; i < 8; ++i) {
        float t = e[i] * scl[i] + sft[i];
        y[i] = t > 0.f ? t : SLOPE * t;
    }
}
__device__ __forceinline__ void gload_lds16(const void* g, void* l) {
    __builtin_amdgcn_global_load_lds((__attribute__((address_space(1))) void*)g,
                                     (__attribute__((address_space(3))) void*)l, 16, 0, 0);
}

// ---- prep (weights->bf16 transposed, zero GN partials) + reorder x -> T0(conv1) ----
__global__ __launch_bounds__(256) void prep_reorder_k(
    const float* __restrict__ x, unsigned* __restrict__ t0,
    const float* __restrict__ W1, const float* __restrict__ Wr, const float* __restrict__ W2,
    unsigned short* __restrict__ Wt1, unsigned short* __restrict__ Wtr, unsigned short* __restrict__ Wt2,
    float* __restrict__ part)
{
    int bid = blockIdx.x;
    if (bid < 6144) {                    // reorder: idx < V*32 dwords
        int idx = bid * 256 + threadIdx.x;
        int v = idx >> 5, j2 = idx & 31;
        int b = j2 >> 4, f0 = (j2 & 15) * 2;
        const float* p = x + ((size_t)b * V + v) * 32 + f0;
        t0[idx] = pk2(p[0], p[1]);
    } else {
        int i = (bid - 6144) * 256 + threadIdx.x;
        if (i < 32768) {                 // Wt2[kk][o][f] = W2[kk][f][o], F=64
            int kk = i >> 12, rem = i & 4095, o = rem >> 6, f = rem & 63;
            Wt2[i] = f2us(W2[kk * 4096 + f * 64 + o]);
        } else if (i < 49152) {          // Wt1, F=32
            int j = i - 32768;
            int kk = j >> 11, rem = j & 2047, o = rem >> 5, f = rem & 31;
            Wt1[j] = f2us(W1[kk * 2048 + f * 64 + o]);
        } else if (i < 65536) {          // Wtr, F=32
            int j = i - 49152;
            int kk = j >> 11, rem = j & 2047, o = rem >> 5, f = rem & 31;
            Wtr[j] = f2us(Wr[kk * 2048 + f * 64 + o]);
        } else if (i < 66560) {
            part[i - 65536] = 0.f;
        }
    }
}

// ---- SpMM Chebyshev step: zn = 2*(L@zc) - zp (bf16 rows). 32B (2 uint4) per thread. ----
template<int THR, bool FIRST>
__global__ __launch_bounds__(256) void spmm_step(
    const uint4* __restrict__ zc, const uint4* __restrict__ zp, uint4* __restrict__ zn,
    const float* __restrict__ vals, const int* __restrict__ col)
{
    constexpr int L4 = THR * 2;
    int tid = blockIdx.x * 256 + threadIdx.x;
    int v = tid / THR;
    int c = (tid - v * THR) * 2;
    int base = v * NNZ;
    float t[16];
    #pragma unroll
    for (int i = 0; i < 16; ++i) t[i] = 0.f;
    #pragma unroll
    for (int n = 0; n < NNZ; ++n) {
        float a = vals[base + n];
        int cc = col[base + n];
        const uint4* p = zc + (size_t)cc * L4 + c;
        fma8(t, a, p[0]);
        fma8(t + 8, a, p[1]);
    }
    if (!FIRST) {
        const uint4* pp = zp + (size_t)v * L4 + c;
        fold8(t, pp[0]);
        fold8(t + 8, pp[1]);
    }
    uint4* q = zn + (size_t)v * L4 + c;
    q[0] = pack8(t);
    q[1] = pack8(t + 8);
}

// ---- conv2 steps 1 & 2 with GN1 fused (T0 never materialized) ----
// MODE 0: T1 = L @ GN(ACC)           (gather applies GN+LeakyReLU on the fly)
// MODE 1: T2 = 2*(L @ T1) - GN(ACC)  (fold recomputes GN for own row)
template<int MODE>
__global__ __launch_bounds__(256) void spmm2_gn(
    const unsigned short* __restrict__ ACC, const uint4* __restrict__ zc,
    uint4* __restrict__ zn, const float* __restrict__ part,
    const float* __restrict__ gamma, const float* __restrict__ beta,
    const float* __restrict__ vals, const int* __restrict__ col)
{
    int tid = blockIdx.x * 256 + threadIdx.x;     // over V*8
    int v = tid >> 3;
    int c2 = (tid & 7) * 2;                       // chunk pair (same batch)
    int b = c2 >> 3;
    int ch0 = (c2 & 7) * 8;                       // first of 16 channels
    const float Nf = (float)V * 8.f;
    int g0 = c2 & 7;
    float m0 = part[(b*8+g0)*2] / Nf;
    float r0 = rsqrtf(part[(b*8+g0)*2+1]/Nf - m0*m0 + EPSV);
    float m1 = part[(b*8+g0+1)*2] / Nf;
    float r1 = rsqrtf(part[(b*8+g0+1)*2+1]/Nf - m1*m1 + EPSV);
    float scl[16], sft[16];
    #pragma unroll
    for (int i = 0; i < 8; ++i) {
        int o = ch0 + i;
        scl[i] = r0 * gamma[o];     sft[i] = beta[o] - m0 * scl[i];
        scl[8+i] = r1 * gamma[o+8]; sft[8+i] = beta[o+8] - m1 * scl[8+i];
    }

    float t[16];
    #pragma unroll
    for (int i = 0; i < 16; ++i) t[i] = 0.f;
    int base = v * NNZ;
    #pragma unroll
    for (int n = 0; n < NNZ; ++n) {
        float a = vals[base + n];
        int cc = col[base + n];
        if constexpr (MODE == 0) {
            const uint4* p = (const uint4*)(const void*)(ACC + ((size_t)b * V + cc) * 64 + ch0);
            float y[8];
            gnleaky8(p[0], scl, sft, y);
            #pragma unroll
            for (int i = 0; i < 8; ++i) t[i] += a * y[i];
            gnleaky8(p[1], scl + 8, sft + 8, y);
            #pragma unroll
            for (int i = 0; i < 8; ++i) t[8 + i] += a * y[i];
        } else {
            const uint4* p = zc + (size_t)cc * 16 + c2;
            fma8(t, a, p[0]);
            fma8(t + 8, a, p[1]);
        }
    }
    if constexpr (MODE == 1) {
        const uint4* pp = (const uint4*)(const void*)(ACC + ((size_t)b * V + v) * 64 + ch0);
        float y[8];
        gnleaky8(pp[0], scl, sft, y);
        #pragma unroll
        for (int i = 0; i < 8; ++i) t[i] = 2.f * t[i] - y[i];
        gnleaky8(pp[1], scl + 8, sft + 8, y);
        #pragma unroll
        for (int i = 0; i < 8; ++i) t[8 + i] = 2.f * t[8 + i] - y[i];
    }
    uint4* q = zn + (size_t)v * 16 + c2;
    q[0] = pack8(t);
    q[1] = pack8(t + 8);
}

// ---- conv1 GEMM (F=32, dual W1/Wr) with T7 computed in-kernel ----
__global__ __launch_bounds__(256) void gemm1f(
    const unsigned short* __restrict__ T,        // slot pitch V*64
    const unsigned short* __restrict__ WtA, const unsigned short* __restrict__ WtB,
    const float* __restrict__ biasA, const float* __restrict__ biasB,
    const float* __restrict__ vals, const int* __restrict__ col,
    unsigned short* __restrict__ ACC, float* __restrict__ resOut, float* __restrict__ part)
{
    __shared__ unsigned short shraw[34816];      // 64KB tile / 68KB epilogue overlay
    __shared__ float sGrp[32];
    unsigned short* tile = shraw;
    float* accbuf  = (float*)shraw;
    float* dualbuf = accbuf + 2 * 64 * RST;

    int wv = threadIdx.x >> 6, lane = threadIdx.x & 63;
    int quad = lane >> 4, l15 = lane & 15;
    int v0 = blockIdx.x * 64;
    int ot = wv;

    // DMA-stage slices 0..6 (pre-swizzled global source, linear LDS)
    #pragma unroll
    for (int i = 0; i < 14; ++i) {
        int s = (i * 4 + wv) * 64 + lane;        // 16B-chunk id
        int kkl = s >> 9;                        // /512 (64 rows * 8 chunks)
        int ws = s & 511;
        int row = ws >> 3;
        int cl = ws & 7;
        int cg = cl ^ (row & 7);
        const unsigned short* gp = T + ((size_t)kkl * V + v0 + row) * 64 + cg * 8;
        gload_lds16(gp, tile + (size_t)(i * 4 + wv) * 64 * 8);
    }

    // compute T7 tile in-kernel: t7 = 2*(L@T6) - T5 (own 64 rows), ds_write slice 7
    {
        const unsigned short* T6 = T + (size_t)6 * V * 64;
        const unsigned short* T5 = T + (size_t)5 * V * 64;
        int row = threadIdx.x >> 2, c2 = (threadIdx.x & 3) * 2;
        int gv = v0 + row;
        float t[16];
        #pragma unroll
        for (int i = 0; i < 16; ++i) t[i] = 0.f;
        int base = gv * NNZ;
        #pragma unroll
        for (int n = 0; n < NNZ; ++n) {
            float a = vals[base + n];
            int cc = col[base + n];
            const uint4* p = (const uint4*)(const void*)(T6 + (size_t)cc * 64 + c2 * 8);
            fma8(t, a, p[0]);
            fma8(t + 8, a, p[1]);
        }
        const uint4* pp = (const uint4*)(const void*)(T5 + (size_t)gv * 64 + c2 * 8);
        fold8(t, pp[0]);
        fold8(t + 8, pp[1]);
        uint4* tl = (uint4*)tile;
        int r7 = row & 7;
        tl[(7 * 64 + row) * 8 + (c2 ^ r7)]       = pack8(t);
        tl[(7 * 64 + row) * 8 + ((c2 + 1) ^ r7)] = pack8(t + 8);
    }

    // hoist B fragments while DMA in flight
    bf16x8 bw[8], bd[8];
    #pragma unroll
    for (int kk = 0; kk < 8; ++kk) {
        size_t brow = ((size_t)kk * 64 + ot * 16 + l15) * 32 + quad * 8;
        bw[kk] = *(const bf16x8*)(const void*)(WtA + brow);
        bd[kk] = *(const bf16x8*)(const void*)(WtB + brow);
    }
    f32x4 acc[4][2], accd[4][2];
    #pragma unroll
    for (int m = 0; m < 4; ++m)
        #pragma unroll
        for (int b = 0; b < 2; ++b) {
            acc[m][b]  = (f32x4){0.f, 0.f, 0.f, 0.f};
            accd[m][b] = (f32x4){0.f, 0.f, 0.f, 0.f};
        }
    __syncthreads();

    #pragma unroll
    for (int kk = 0; kk < 8; ++kk) {
        #pragma unroll
        for (int m = 0; m < 4; ++m) {
            int r = m * 16 + l15;
            int rx = r & 7;
            const unsigned short* rbase = tile + ((size_t)kk * 64 + r) * 64;
            #pragma unroll
            for (int b = 0; b < 2; ++b) {
                int s0 = (b * 4 + quad) ^ rx;
                bf16x8 a = *(const bf16x8*)(const void*)(rbase + s0 * 8);
                acc[m][b]  = __builtin_amdgcn_mfma_f32_16x16x32_bf16(a, bw[kk], acc[m][b], 0, 0, 0);
                accd[m][b] = __builtin_amdgcn_mfma_f32_16x16x32_bf16(a, bd[kk], accd[m][b], 0, 0, 0);
            }
        }
    }

    // epilogue: h1 -> ACC (bf16) + GN1 partials; res -> out (f32)
    __syncthreads();
    int o = ot * 16 + l15;
    float biA = biasA[o], biB = biasB[o];
    #pragma unroll
    for (int m = 0; m < 4; ++m)
        #pragma unroll
        for (int b = 0; b < 2; ++b)
            #pragma unroll
            for (int rr = 0; rr < 4; ++rr) {
                int r = m * 16 + quad * 4 + rr;
                accbuf[(b * 64 + r) * RST + o] = acc[m][b][rr] + biA;
                dualbuf[(b * 64 + r) * RST + o] = accd[m][b][rr] + biB;
            }
    if (threadIdx.x < 32) sGrp[threadIdx.x] = 0.f;
    __syncthreads();
    #pragma unroll
    for (int j = 0; j < 4; ++j) {
        int cid = threadIdx.x + 256 * j;          // 0..1023
        int g = cid & 7, r = (cid >> 3) & 63, b = cid >> 9;
        const float* src = accbuf + (b * 64 + r) * RST + g * 8;
        float e[8], s = 0.f, q = 0.f;
        #pragma unroll
        for (int i = 0; i < 8; ++i) { e[i] = src[i]; s += e[i]; q += e[i] * e[i]; }
        *(uint4*)(void*)(ACC + ((size_t)b * V + v0 + r) * 64 + g * 8) = pack8(e);
        atomicAdd(&sGrp[b * 8 + g], s);
        atomicAdd(&sGrp[16 + b * 8 + g], q);
    }
    #pragma unroll
    for (int j = 0; j < 8; ++j) {
        int cid = threadIdx.x + 256 * j;          // 0..2047 float4 chunks
        int oc = cid & 15, r = (cid >> 4) & 63, b = cid >> 10;
        float4 vv = *(const float4*)(const void*)(dualbuf + (b * 64 + r) * RST + oc * 4);
        *(float4*)(void*)(resOut + ((size_t)b * V + v0 + r) * 64 + oc * 4) = vv;
    }
    __syncthreads();
    if (threadIdx.x < 16) {
        atomicAdd(&part[threadIdx.x * 2],     sGrp[threadIdx.x]);
        atomicAdd(&part[threadIdx.x * 2 + 1], sGrp[16 + threadIdx.x]);
    }
}

// ---- conv2 GEMM (F=64) with slot0 = GN(ACC) staged in-kernel and T7 computed in-kernel ----
__global__ __launch_bounds__(256) void gemm2f(
    const unsigned short* __restrict__ T,        // slot pitch V*128
    unsigned short* ACC,                         // read h1 (slot0 GN) / write h2 (no restrict!)
    const float* __restrict__ part1, const float* __restrict__ g1, const float* __restrict__ be1,
    const unsigned short* __restrict__ Wt2, const float* __restrict__ biasA,
    float* __restrict__ part2,
    const float* __restrict__ vals, const int* __restrict__ col)
{
    __shared__ unsigned short shraw[32768];      // 64 KB (4 slices per phase)
    __shared__ float sGrp[32];
    unsigned short* tile = shraw;
    float* accbuf = (float*)shraw;

    int wv = threadIdx.x >> 6, lane = threadIdx.x & 63;
    int quad = lane >> 4, l15 = lane & 15;
    int v0 = blockIdx.x * 64;
    int ot = wv;
    const float Nf = (float)V * 8.f;

    // ---- phase 0: DMA slices 1..3, GN-stage slot 0 ----
    #pragma unroll
    for (int i = 4; i < 16; ++i) {
        int s = (i * 4 + wv) * 64 + lane;
        int kkl = s >> 10;                       // 1..3
        int ws = s & 1023;
        int row = ws >> 4;
        int cl = ws & 15;
        int cg = (cl & ~7) | ((cl & 7) ^ (row & 7));
        const unsigned short* gp = T + ((size_t)kkl * V + v0 + row) * 128 + cg * 8;
        gload_lds16(gp, tile + (size_t)(i * 4 + wv) * 64 * 8);
    }
    {
        int cl = threadIdx.x & 15;
        int b = cl >> 3, g = cl & 7, j8 = b * 8 + g;
        float mean = part1[j8 * 2] / Nf;
        float rstd = rsqrtf(part1[j8 * 2 + 1] / Nf - mean * mean + EPSV);
        int o0 = g * 8;
        float scl[8], sft[8];
        #pragma unroll
        for (int i = 0; i < 8; ++i) {
            scl[i] = rstd * g1[o0 + i];
            sft[i] = be1[o0 + i] - mean * scl[i];
        }
        uint4* tl = (uint4*)tile;
        #pragma unroll
        for (int j = 0; j < 4; ++j) {
            int r = (threadIdx.x >> 4) + 16 * j;
            uint4 aa = *(const uint4*)(const void*)(ACC + ((size_t)b * V + v0 + r) * 64 + o0);
            float y[8];
            gnleaky8(aa, scl, sft, y);
            tl[r * 16 + ((cl & ~7) | ((cl & 7) ^ (r & 7)))] = pack8(y);
        }
    }
    // hoist B fragments
    bf16x8 bw[8][2];
    #pragma unroll
    for (int kk = 0; kk < 8; ++kk)
        #pragma unroll
        for (int fh = 0; fh < 2; ++fh) {
            size_t brow = ((size_t)kk * 64 + ot * 16 + l15) * 64 + fh * 32 + quad * 8;
            bw[kk][fh] = *(const bf16x8*)(const void*)(Wt2 + brow);
        }
    f32x4 acc[4][2];
    #pragma unroll
    for (int m = 0; m < 4; ++m)
        #pragma unroll
        for (int b = 0; b < 2; ++b) acc[m][b] = (f32x4){0.f, 0.f, 0.f, 0.f};
    __syncthreads();

    #pragma unroll
    for (int kkl = 0; kkl < 4; ++kkl) {          // slices 0..3
        #pragma unroll
        for (int m = 0; m < 4; ++m) {
            int r = m * 16 + l15, rx = r & 7;
            const unsigned short* rbase = tile + ((size_t)kkl * 64 + r) * 128;
            #pragma unroll
            for (int b = 0; b < 2; ++b)
                #pragma unroll
                for (int fh = 0; fh < 2; ++fh) {
                    int c0 = b * 8 + fh * 4 + quad;
                    int s0 = (c0 & ~7) | ((c0 & 7) ^ rx);
                    bf16x8 a = *(const bf16x8*)(const void*)(rbase + s0 * 8);
                    acc[m][b] = __builtin_amdgcn_mfma_f32_16x16x32_bf16(a, bw[kkl][fh], acc[m][b], 0, 0, 0);
                }
        }
    }
    __syncthreads();                              // phase-0 tile consumed

    // ---- phase 1: DMA slices 4..6 (local 0..2), compute T7 (local 3) ----
    #pragma unroll
    for (int i = 0; i < 12; ++i) {
        int s = (i * 4 + wv) * 64 + lane;
        int kkl = s >> 10;                       // 0..2 -> global 4..6
        int ws = s & 1023;
        int row = ws >> 4;
        int cl = ws & 15;
        int cg = (cl & ~7) | ((cl & 7) ^ (row & 7));
        const unsigned short* gp = T + ((size_t)(4 + kkl) * V + v0 + row) * 128 + cg * 8;
        gload_lds16(gp, tile + (size_t)(i * 4 + wv) * 64 * 8);
    }
    {
        const unsigned short* T6 = T + (size_t)6 * V * 128;
        const unsigned short* T5 = T + (size_t)5 * V * 128;
        int row = threadIdx.x >> 2, cb = (threadIdx.x & 3) * 4;
        int gv = v0 + row;
        float t[32];
        #pragma unroll
        for (int i = 0; i < 32; ++i) t[i] = 0.f;
        int base = gv * NNZ;
        #pragma unroll
        for (int n = 0; n < NNZ; ++n) {
            float a = vals[base + n];
            int cc = col[base + n];
            const uint4* p = (const uint4*)(const void*)(T6 + (size_t)cc * 128 + cb * 8);
            fma8(t, a, p[0]);
            fma8(t + 8, a, p[1]);
            fma8(t + 16, a, p[2]);
            fma8(t + 24, a, p[3]);
        }
        const uint4* pp = (const uint4*)(const void*)(T5 + (size_t)gv * 128 + cb * 8);
        fold8(t, pp[0]);
        fold8(t + 8, pp[1]);
        fold8(t + 16, pp[2]);
        fold8(t + 24, pp[3]);
        uint4* tl = (uint4*)tile;
        int r7 = row & 7;
        #pragma unroll
        for (int q = 0; q < 4; ++q) {
            int c = cb + q;
            tl[(3 * 64 + row) * 16 + ((c & ~7) | ((c & 7) ^ r7))] = pack8(t + q * 8);
        }
    }
    __syncthreads();

    #pragma unroll
    for (int kkl = 0; kkl < 4; ++kkl) {          // local slices -> global kk 4..7
        int kk = 4 + kkl;
        #pragma unroll
        for (int m = 0; m < 4; ++m) {
            int r = m * 16 + l15, rx = r & 7;
            const unsigned short* rbase = tile + ((size_t)kkl * 64 + r) * 128;
            #pragma unroll
            for (int b = 0; b < 2; ++b)
                #pragma unroll
                for (int fh = 0; fh < 2; ++fh) {
                    int c0 = b * 8 + fh * 4 + quad;
                    int s0 = (c0 & ~7) | ((c0 & 7) ^ rx);
                    bf16x8 a = *(const bf16x8*)(const void*)(rbase + s0 * 8);
                    acc[m][b] = __builtin_amdgcn_mfma_f32_16x16x32_bf16(a, bw[kk][fh], acc[m][b], 0, 0, 0);
                }
        }
    }

    // epilogue: pre-GN h2 -> ACC (bf16) + GN2 partials
    __syncthreads();
    int o = ot * 16 + l15;
    float biA = biasA[o];
    #pragma unroll
    for (int m = 0; m < 4; ++m)
        #pragma unroll
        for (int b = 0; b < 2; ++b)
            #pragma unroll
            for (int rr = 0; rr < 4; ++rr) {
                int r = m * 16 + quad * 4 + rr;
                accbuf[(b * 64 + r) * RST + o] = acc[m][b][rr] + biA;
            }
    if (threadIdx.x < 32) sGrp[threadIdx.x] = 0.f;
    __syncthreads();
    #pragma unroll
    for (int j = 0; j < 4; ++j) {
        int cid = threadIdx.x + 256 * j;
        int g = cid & 7, r = (cid >> 3) & 63, b = cid >> 9;
        const float* src = accbuf + (b * 64 + r) * RST + g * 8;
        float e[8], s = 0.f, q = 0.f;
        #pragma unroll
        for (int i = 0; i < 8; ++i) { e[i] = src[i]; s += e[i]; q += e[i] * e[i]; }
        *(uint4*)(void*)(ACC + ((size_t)b * V + v0 + r) * 64 + g * 8) = pack8(e);
        atomicAdd(&sGrp[b * 8 + g], s);
        atomicAdd(&sGrp[16 + b * 8 + g], q);
    }
    __syncthreads();
    if (threadIdx.x < 16) {
        atomicAdd(&part2[threadIdx.x * 2],     sGrp[threadIdx.x]);
        atomicAdd(&part2[threadIdx.x * 2 + 1], sGrp[16 + threadIdx.x]);
    }
}

// ---- final: out (holds res) += LeakyReLU(GN2(ACC)) ----
__global__ __launch_bounds__(256) void final_out(const unsigned short* __restrict__ ACC,
                                                 float* outres,
                                                 const float* __restrict__ part,
                                                 const float* __restrict__ gamma, const float* __restrict__ beta) {
    int idx = blockIdx.x * 256 + threadIdx.x;
    int b = idx >= V * 8 ? 1 : 0;
    int r = idx - b * V * 8;
    int v = r >> 3, g = r & 7;
    int j = b * 8 + g;
    const float N = (float)V * 8.f;
    float mean = part[j * 2] / N;
    float rstd = rsqrtf(part[j * 2 + 1] / N - mean * mean + EPSV);
    int o0 = g * 8;
    size_t base = ((size_t)b * V + v) * 64 + o0;
    uint4 aa = *(const uint4*)(const void*)(ACC + base);
    float e[8] = { lo2f(aa.x), hi2f(aa.x), lo2f(aa.y), hi2f(aa.y),
                   lo2f(aa.z), hi2f(aa.z), lo2f(aa.w), hi2f(aa.w) };
    float4 r0 = *(const float4*)(const void*)(outres + base);
    float4 r1 = *(const float4*)(const void*)(outres + base + 4);
    float y[8];
    #pragma unroll
    for (int i = 0; i < 8; ++i) {
        float t = (e[i] - mean) * rstd * gamma[o0 + i] + beta[o0 + i];
        y[i] = t > 0.f ? t : SLOPE * t;
    }
    float4 w0 = { y[0] + r0.x, y[1] + r0.y, y[2] + r0.z, y[3] + r0.w };
    float4 w1 = { y[4] + r1.x, y[5] + r1.y, y[6] + r1.z, y[7] + r1.w };
    *(float4*)(void*)(outres + base) = w0;
    *(float4*)(void*)(outres + base + 4) = w1;
}

extern "C" void kernel_launch(void* const* d_in, const int* in_sizes, int n_in,
                              void* d_out, int out_size, void* d_ws, size_t ws_size,
                              hipStream_t stream) {
    const float* x    = (const float*)d_in[0];
    const float* vals = (const float*)d_in[1];
    const int*   col  = (const int*)d_in[3];
    const float* W1   = (const float*)d_in[4];
    const float* b1   = (const float*)d_in[5];
    const float* g1   = (const float*)d_in[6];
    const float* be1  = (const float*)d_in[7];
    const float* W2   = (const float*)d_in[8];
    const float* b2   = (const float*)d_in[9];
    const float* g2   = (const float*)d_in[10];
    const float* be2  = (const float*)d_in[11];
    const float* Wr   = (const float*)d_in[12];
    const float* br   = (const float*)d_in[13];
    float* out = (float*)d_out;

    // workspace:
    //   TS   bf16 8*[V][128]  (conv1 uses first half of each slot as [V][64])
    //   ACC  bf16 [2][V][64] | Wt1/Wtr/Wt2 bf16 | PART1[32] PART2[32] f32
    unsigned short* TS  = (unsigned short*)d_ws;
    unsigned short* ACC = TS + (size_t)8 * V * 128;
    unsigned short* Wt1 = ACC + (size_t)2 * V * 64;
    unsigned short* Wtr = Wt1 + 8 * 64 * 32;
    unsigned short* Wt2 = Wtr + 8 * 64 * 32;
    float* PART1 = (float*)(Wt2 + 8 * 64 * 64);
    float* PART2 = PART1 + 32;

    prep_reorder_k<<<6404, 256, 0, stream>>>(x, (unsigned*)TS, W1, Wr, W2, Wt1, Wtr, Wt2, PART1);

    // ---- conv1 basis: T1..T6 (T7 computed inside gemm1f) ----
    uint4* T1s[8];
    for (int k = 0; k < 8; ++k) T1s[k] = (uint4*)(TS + (size_t)k * V * 64);
    spmm_step<4, true><<<V * 4 / 256, 256, 0, stream>>>(T1s[0], nullptr, T1s[1], vals, col);
    for (int k = 2; k < 7; ++k)
        spmm_step<4, false><<<V * 4 / 256, 256, 0, stream>>>(T1s[k-1], T1s[k-2], T1s[k], vals, col);

    gemm1f<<<V / 64, 256, 0, stream>>>(TS, Wt1, Wtr, b1, br, vals, col, ACC, out, PART1);

    // ---- conv2: GN1 fused into steps 1-2 and gemm2f slot-0; T7 inside gemm2f ----
    uint4* T2s[8];
    for (int k = 0; k < 8; ++k) T2s[k] = (uint4*)(TS + (size_t)k * V * 128);
    spmm2_gn<0><<<V * 8 / 256, 256, 0, stream>>>(ACC, nullptr, T2s[1], PART1, g1, be1, vals, col);
    spmm2_gn<1><<<V * 8 / 256, 256, 0, stream>>>(ACC, T2s[1], T2s[2], PART1, g1, be1, vals, col);
    for (int k = 3; k < 7; ++k)
        spmm_step<8, false><<<V * 8 / 256, 256, 0, stream>>>(T2s[k-1], T2s[k-2], T2s[k], vals, col);

    gemm2f<<<V / 64, 256, 0, stream>>>(TS, ACC, PART1, g1, be1, Wt2, b2, PART2, vals, col);

    final_out<<<2 * V * 8 / 256, 256, 0, stream>>>(ACC, out, PART2, g2, be2);
}